// Round 2
// baseline (386.741 us; speedup 1.0000x reference)
//
#include <hip/hip_runtime.h>
#include <stdint.h>

// ---------------------------------------------------------------------------
// GCN 2-layer: out = Ahat( dropout(elu( Ahat(x@W1)+b1 )) @ W2 ) + b2
// Ahat = D^-1/2 (A+I) D^-1/2
// dropout = jax threefry2x32 key(42), p=0.25, partitionable path.
// R11->R12: GEMM restructured barrier-free. R11 counters showed k_gemm_mfma
// (66us) with MfmaUtil 7% / VALU 6% / HBM 15% -> pure latency serialization:
// 16 K-steps x (vmcnt(0)+s_barrier) each eats full L3/HBM latency of the A
// prefetch. New design: NO LDS, NO barriers. Each lane loads its MFMA
// A-fragment directly (8 consecutive fp32 of one row -> 2x float4, cvt to
// fp16 in-register; VALU was idle). A-tile read 4x (once per column-wave)
// from L2/L3 -- ~410MB vs 34.5TB/s L2, cheap. Depth-1 register pipeline
// (static [2] stages, full unroll) gives unbroken per-wave ILP chains.
// ---------------------------------------------------------------------------

typedef float floatx4 __attribute__((ext_vector_type(4)));
typedef _Float16 f16;
typedef _Float16 f16x8 __attribute__((ext_vector_type(8)));

union F16x8 {
  f16x8 v;
  f16 e[8];
  uint4 q;
};

// ---------------- Threefry-2x32, key = (0, 42), 20 rounds ------------------
__device__ __forceinline__ void tf_round(uint32_t& x0, uint32_t& x1, int r) {
  x0 += x1;
  x1 = (x1 << r) | (x1 >> (32 - r));
  x1 ^= x0;
}

__device__ __forceinline__ void threefry_0_42(uint32_t c0, uint32_t c1,
                                              uint32_t& o0, uint32_t& o1) {
  const uint32_t ks0 = 0u;
  const uint32_t ks1 = 42u;
  const uint32_t ks2 = 0x1BD11BDAu ^ 0u ^ 42u;
  uint32_t x0 = c0 + ks0;
  uint32_t x1 = c1 + ks1;
  tf_round(x0, x1, 13); tf_round(x0, x1, 15); tf_round(x0, x1, 26); tf_round(x0, x1, 6);
  x0 += ks1; x1 += ks2 + 1u;
  tf_round(x0, x1, 17); tf_round(x0, x1, 29); tf_round(x0, x1, 16); tf_round(x0, x1, 24);
  x0 += ks2; x1 += ks0 + 2u;
  tf_round(x0, x1, 13); tf_round(x0, x1, 15); tf_round(x0, x1, 26); tf_round(x0, x1, 6);
  x0 += ks0; x1 += ks1 + 3u;
  tf_round(x0, x1, 17); tf_round(x0, x1, 29); tf_round(x0, x1, 16); tf_round(x0, x1, 24);
  x0 += ks1; x1 += ks2 + 4u;
  tf_round(x0, x1, 13); tf_round(x0, x1, 15); tf_round(x0, x1, 26); tf_round(x0, x1, 6);
  x0 += ks2; x1 += ks0 + 5u;
  o0 = x0; o1 = x1;
}

// mask byte for features [8b, 8b+8): bit i set = keep (u < 0.75)
__device__ __forceinline__ unsigned char mask_byte(uint32_t b) {
  uint32_t jb = b << 3;
  uint32_t m = 0;
#pragma unroll
  for (int i = 0; i < 8; ++i) {
    uint32_t r0, r1;
    threefry_0_42(0u, jb + (uint32_t)i, r0, r1);
    uint32_t bits = r0 ^ r1;
    // u = bitcast((bits>>9)|0x3f800000)-1 < 0.75  <=>  bits < 0xC0000000 (exact)
    m |= (bits < 0xC0000000u ? 1u : 0u) << i;
  }
  return (unsigned char)m;
}

// ---------------- degree (+ dropout-mask bytes [0,nb0)) --------------------
__global__ void k_deg(const int* __restrict__ dst, int E, int* __restrict__ deg,
                      unsigned char* __restrict__ maskb, int nb0) {
  int t = blockIdx.x * blockDim.x + threadIdx.x;
  if (t < E) atomicAdd(&deg[dst[t]], 1);
  if (t < nb0) maskb[t] = mask_byte((uint32_t)t);
}

// ---------------- 3-phase exclusive scan (+ dinv fused) --------------------
__global__ __launch_bounds__(256) void k_scan1(const int* __restrict__ deg,
                                               int* __restrict__ excl,
                                               int* __restrict__ sums,
                                               float* __restrict__ dinv, int N) {
  __shared__ int sm[256];
  int tid = threadIdx.x;
  int i = blockIdx.x * 256 + tid;
  int v = (i < N) ? deg[i] : 0;
  if (i < N) dinv[i] = 1.0f / sqrtf((float)(v + 1));  // +1 self loop
  sm[tid] = v;
  __syncthreads();
#pragma unroll
  for (int off = 1; off < 256; off <<= 1) {
    int t = (tid >= off) ? sm[tid - off] : 0;
    __syncthreads();
    sm[tid] += t;
    __syncthreads();
  }
  if (i < N) excl[i] = sm[tid] - v;
  if (tid == 255) sums[blockIdx.x] = sm[255];
}

__global__ __launch_bounds__(1024) void k_scan2(int* __restrict__ sums, int nb) {
  __shared__ int sm[1024];
  int tid = threadIdx.x;
  int v = (tid < nb) ? sums[tid] : 0;
  sm[tid] = v;
  __syncthreads();
#pragma unroll
  for (int off = 1; off < 1024; off <<= 1) {
    int t = (tid >= off) ? sm[tid - off] : 0;
    __syncthreads();
    sm[tid] += t;
    __syncthreads();
  }
  if (tid < nb) sums[tid] = sm[tid] - v;  // exclusive, in place
}

__global__ void k_scan3(int* __restrict__ rowptr, int* __restrict__ cursor,
                        const int* __restrict__ sums, int N, int E) {
  int i = blockIdx.x * blockDim.x + threadIdx.x;
  if (i < N) {
    int r = rowptr[i] + sums[i >> 8];
    rowptr[i] = r;
    cursor[i] = r;
  }
  if (i == 0) rowptr[N] = E;
}

// ---------------- bucket edges by dst (+ mask bytes [nb0,nb0+nb1)) ---------
__global__ void k_bucket(const int* __restrict__ src, const int* __restrict__ dst,
                         int* __restrict__ cursor, int* __restrict__ csr_src, int E,
                         unsigned char* __restrict__ maskb, int nb0, int nb1) {
  int t = blockIdx.x * blockDim.x + threadIdx.x;
  if (t < E) {
    int pos = atomicAdd(&cursor[dst[t]], 1);
    csr_src[pos] = src[t];
  }
  if (t < nb1) maskb[nb0 + t] = mask_byte((uint32_t)(nb0 + t));
}

// -------- prep: W1 [512][256] fp32 -> packed fragment-major fp16 -----------
// uint4 entry index = (ks*16 + nt)*64 + lane; 8 fp16 each.
// lane = quad*16 + (n&15), k = ks*32 + quad*8 + j, nt = n>>4.
__global__ void k_prep_w1t(const float* __restrict__ W1,
                           f16* __restrict__ Bpk) {
  int t = blockIdx.x * blockDim.x + threadIdx.x;  // t = k*256+n
  if (t >= 512 * 256) return;
  int k = t >> 8, n = t & 255;
  int ks = k >> 5, quad = (k >> 3) & 3, j = k & 7;
  int nt = n >> 4, lane = quad * 16 + (n & 15);
  size_t e = ((size_t)(ks * 16 + nt)) * 64 + lane;
  Bpk[e * 8 + j] = (f16)W1[t];
}

// -------- GEMM1: hs = (f16) dinv ⊙ (x @ W1), single fp16 MFMA --------------
// Barrier-free, LDS-free. Wave tile 64 rows x 64 cols; 4 waves/block cover
// 256 cols. Each lane loads its A-fragment directly from global (8
// consecutive fp32 -> 2x float4 -> cvt fp16), B fragments from the packed
// L2-resident plane. Depth-1 register pipeline, statically indexed, fully
// unrolled (no dynamic indexing -> no scratch).
__global__ __launch_bounds__(256) void k_gemm_mfma(
    const float* __restrict__ A,     // [M,512]
    const uint4* __restrict__ Bpk,   // packed fp16, 16384 uint4 (256 KB)
    const float* __restrict__ dinv,  // [M]
    f16* __restrict__ C,             // [M,256] scaled output
    int M) {
  const int tid = threadIdx.x;
  const int cg = tid >> 6;           // wave id = column group (nt = cg*4..+3)
  const int lane = tid & 63;
  const int quad = lane >> 4;
  const int l16 = lane & 15;
  const int m0 = blockIdx.x * 64;

  // per-lane A fragment base pointers: row = m0 + fr*16 + l16, k0 = quad*8
  const float* ap[4];
#pragma unroll
  for (int fr = 0; fr < 4; ++fr) {
    int r = m0 + fr * 16 + l16;
    if (r >= M) r = M - 1;           // clamp (C write is guarded)
    ap[fr] = A + (size_t)r * 512 + quad * 8;
  }
  const uint4* bp0 = Bpk + lane + (size_t)(cg * 4) * 64;

  auto cvt8 = [](float4 a, float4 b) {
    F16x8 r;
    r.e[0] = (f16)a.x; r.e[1] = (f16)a.y; r.e[2] = (f16)a.z; r.e[3] = (f16)a.w;
    r.e[4] = (f16)b.x; r.e[5] = (f16)b.y; r.e[6] = (f16)b.z; r.e[7] = (f16)b.w;
    return r;
  };

  floatx4 acc[4][4];  // [row-frag][col-tile]
#pragma unroll
  for (int fr = 0; fr < 4; ++fr)
#pragma unroll
    for (int t = 0; t < 4; ++t) acc[fr][t] = (floatx4){0.f, 0.f, 0.f, 0.f};

  float4 pa[2][4][2];  // [stage][fr][half] fp32 in flight
  uint4 pb[2][4];      // [stage][col-tile]

  // prologue: stage ks=0
#pragma unroll
  for (int fr = 0; fr < 4; ++fr) {
    pa[0][fr][0] = *(const float4*)(ap[fr]);
    pa[0][fr][1] = *(const float4*)(ap[fr] + 4);
  }
#pragma unroll
  for (int t = 0; t < 4; ++t) pb[0][t] = bp0[t * 64];

#pragma unroll
  for (int ks = 0; ks < 16; ++ks) {
    const int cur = ks & 1;
    const int nxt = cur ^ 1;

    // issue next-iteration loads (in flight across this iteration's MFMAs)
    if (ks < 15) {
#pragma unroll
      for (int fr = 0; fr < 4; ++fr) {
        pa[nxt][fr][0] = *(const float4*)(ap[fr] + (ks + 1) * 32);
        pa[nxt][fr][1] = *(const float4*)(ap[fr] + (ks + 1) * 32 + 4);
      }
      const uint4* bp = bp0 + (size_t)(ks + 1) * 1024;
#pragma unroll
      for (int t = 0; t < 4; ++t) pb[nxt][t] = bp[t * 64];
    }

    // compute on current stage
#pragma unroll
    for (int fr = 0; fr < 4; ++fr) {
      F16x8 af = cvt8(pa[cur][fr][0], pa[cur][fr][1]);
#pragma unroll
      for (int t = 0; t < 4; ++t) {
        F16x8 bf;
        bf.q = pb[cur][t];
        acc[fr][t] = __builtin_amdgcn_mfma_f32_16x16x32_f16(af.v, bf.v, acc[fr][t], 0, 0, 0);
      }
    }
  }

  // store hs = dinv[row] * acc; C/D layout col=lane&15, row=quad*4+reg
#pragma unroll
  for (int fr = 0; fr < 4; ++fr)
#pragma unroll
    for (int r = 0; r < 4; ++r) {
      int gm = m0 + fr * 16 + quad * 4 + r;
      if (gm < M) {
        float dv = dinv[gm];
#pragma unroll
        for (int t = 0; t < 4; ++t) {
          const int col = (cg * 4 + t) * 16 + l16;
          C[(size_t)gm * 256 + col] = (f16)(dv * acc[fr][t][r]);
        }
      }
    }
}

// ------- fused gather1 + (+b1 -> elu -> dropout -> dot W2) -----------------
// hs is pre-scaled by dinv. agg[d] = dd*(hs[d] + Σ hs[s]).
// one wave serves TWO nodes (half-wave each); lane covers 8 fp16 feats (16B).
// stores zs[d] = dd * z[d] (pre-scaled for layer-2 gather).
// Accumulation in packed fp16 (v_pk_add_f16); dropout mask from precomputed
// packed-bit table (1.6 MB, L2-hot) instead of in-kernel threefry.
__global__ __launch_bounds__(256) void k_gather_fused(
    const int* __restrict__ rowptr, const int* __restrict__ csr_src,
    const float* __restrict__ dinv, const f16* __restrict__ hs,
    const float* __restrict__ b1, const float* __restrict__ W2,
    const unsigned char* __restrict__ maskb,
    float* __restrict__ zs, int N) {
  int wave = (blockIdx.x * blockDim.x + threadIdx.x) >> 6;
  int lane = threadIdx.x & 63;
  int half = lane >> 5;
  int l = lane & 31;
  int d = wave * 2 + half;
  bool valid = d < N;
  if (!valid) d = N - 1;
  float dd = dinv[d];
  int beg = rowptr[d], end = rowptr[d + 1];
  int f0 = l << 3;  // 8 features per lane

  F16x8 accu;
  accu.q = *(const uint4*)(hs + ((size_t)d << 8) + f0);  // self term
  f16x8 accv = accu.v;

  int e = beg;
  // peel to 16B-aligned csr_src index loads (csr_src is 256B-aligned)
  {
    int pe = beg + ((4 - (beg & 3)) & 3);
    if (pe > end) pe = end;
    for (; e < pe; ++e) {
      F16x8 a;
      a.q = *(const uint4*)(hs + ((size_t)csr_src[e] << 8) + f0);
      accv = accv + a.v;
    }
  }
  for (; e + 3 < end; e += 4) {
    int4 s4 = *(const int4*)(csr_src + e);  // one dwordx4 for 4 indices
    F16x8 a, b, c, dq;
    a.q  = *(const uint4*)(hs + ((size_t)s4.x << 8) + f0);
    b.q  = *(const uint4*)(hs + ((size_t)s4.y << 8) + f0);
    c.q  = *(const uint4*)(hs + ((size_t)s4.z << 8) + f0);
    dq.q = *(const uint4*)(hs + ((size_t)s4.w << 8) + f0);
    f16x8 t0 = a.v + b.v;     // v_pk_add_f16 x4
    f16x8 t1 = c.v + dq.v;
    accv = accv + (t0 + t1);
  }
  for (; e < end; ++e) {
    F16x8 a;
    a.q = *(const uint4*)(hs + ((size_t)csr_src[e] << 8) + f0);
    accv = accv + a.v;
  }
  accu.v = accv;

  // epilogue: scale by dd, bias, elu, masked dropout, dot W2
  float4 bb0 = *(const float4*)(b1 + f0);
  float4 bb1 = *(const float4*)(b1 + f0 + 4);
  float4 w0  = *(const float4*)(W2 + f0);
  float4 w1  = *(const float4*)(W2 + f0 + 4);
  const float* bbp[8] = {&bb0.x, &bb0.y, &bb0.z, &bb0.w, &bb1.x, &bb1.y, &bb1.z, &bb1.w};
  const float* wp[8]  = {&w0.x, &w0.y, &w0.z, &w0.w, &w1.x, &w1.y, &w1.z, &w1.w};

  uint32_t mb = maskb[(size_t)d * 32 + l];  // 8 keep-bits for this lane

  float sum = 0.f;
#pragma unroll
  for (int i = 0; i < 8; ++i) {
    float va = dd * (float)accu.e[i] + *bbp[i];
    float ea = va > 0.f ? va : (__expf(va) - 1.0f);  // elu (fast exp)
    float ha = ((mb >> i) & 1u) ? (ea * (1.0f / 0.75f)) : 0.f;
    sum += ha * *wp[i];
  }
#pragma unroll
  for (int off = 16; off > 0; off >>= 1) sum += __shfl_down(sum, off, 32);
  if (l == 0 && valid) zs[d] = dd * sum;
}

// ------- gather layer 2: out[d] = b2 + dd*(zs[d] + Σ zs[s]) ----------------
// 4 nodes per wave (16 lanes each; avg degree ~16)
__global__ __launch_bounds__(256) void k_gather2(
    const int* __restrict__ rowptr, const int* __restrict__ csr_src,
    const float* __restrict__ dinv, const float* __restrict__ zs,
    const float* __restrict__ b2, float* __restrict__ out, int N) {
  int wave = (blockIdx.x * blockDim.x + threadIdx.x) >> 6;
  int lane = threadIdx.x & 63;
  int sub = lane >> 4;   // 0..3
  int l = lane & 15;
  int d = wave * 4 + sub;
  bool valid = d < N;
  if (!valid) d = N - 1;
  float dd = dinv[d];
  int beg = rowptr[d], end = rowptr[d + 1];

  float acc = 0.f;
  for (int e = beg + l; e < end; e += 16) {
    acc += zs[csr_src[e]];
  }
#pragma unroll
  for (int off = 8; off > 0; off >>= 1) acc += __shfl_down(acc, off, 16);
  if (l == 0 && valid) out[d] = b2[0] + dd * (zs[d] + acc);
}

// ---------------------------------------------------------------------------
extern "C" void kernel_launch(void* const* d_in, const int* in_sizes, int n_in,
                              void* d_out, int out_size, void* d_ws, size_t ws_size,
                              hipStream_t stream) {
  const float* x  = (const float*)d_in[0];
  const int*   ei = (const int*)d_in[1];   // [2,E] int32
  const float* W1 = (const float*)d_in[2];
  const float* b1 = (const float*)d_in[3];
  const float* W2 = (const float*)d_in[4];
  const float* b2 = (const float*)d_in[5];
  float* out = (float*)d_out;

  const int E = in_sizes[1] / 2;
  const int N = in_sizes[0] / 512;  // 50000
  const int* src = ei;
  const int* dst = ei + E;

  char* ws = (char*)d_ws;
  size_t off = 0;
  auto alloc = [&](size_t bytes) -> void* {
    void* p = ws + off;
    off += (bytes + 255) & ~(size_t)255;
    return p;
  };
  int*   deg     = (int*)  alloc((size_t)N * 4);
  int*   rowptr  = (int*)  alloc((size_t)(N + 1) * 4);
  int*   cursor  = (int*)  alloc((size_t)N * 4);
  int*   csr_src = (int*)  alloc((size_t)E * 4);          // 3.2 MB
  int*   sums    = (int*)  alloc(1024 * 4);
  float* dinv    = (float*)alloc((size_t)N * 4);
  f16*   hs      = (f16*)  alloc((size_t)N * 256 * 2);    // 25.6 MB
  float* zs      = (float*)alloc((size_t)N * 4);
  f16*   Bpk     = (f16*)  alloc(512 * 256 * 2);          // 256 KB packed W1
  unsigned char* maskb = (unsigned char*)alloc((size_t)N * 32);  // 1.6 MB mask

  const int nb = (N + 255) / 256;  // scan blocks

  // dropout mask bytes: N*32 total, split across k_deg (first half) and
  // k_bucket (second half) -- both are atomic-latency-bound, VALU idle.
  const int nbytes = N * 32;
  const int nb0 = nbytes >> 1;
  const int nb1 = nbytes - nb0;
  const int tdeg = (E > nb0) ? E : nb0;
  const int tbkt = (E > nb1) ? E : nb1;

  hipMemsetAsync(deg, 0, (size_t)N * 4, stream);
  k_prep_w1t<<<(512 * 256 + 255) / 256, 256, 0, stream>>>(W1, Bpk);
  k_deg<<<(tdeg + 255) / 256, 256, 0, stream>>>(dst, E, deg, maskb, nb0);
  k_scan1<<<nb, 256, 0, stream>>>(deg, rowptr, sums, dinv, N);
  k_scan2<<<1, 1024, 0, stream>>>(sums, nb);
  k_scan3<<<(N + 255) / 256, 256, 0, stream>>>(rowptr, cursor, sums, N, E);
  k_bucket<<<(tbkt + 255) / 256, 256, 0, stream>>>(src, dst, cursor, csr_src, E,
                                                   maskb, nb0, nb1);

  k_gemm_mfma<<<(N + 63) / 64, 256, 0, stream>>>(x, (const uint4*)Bpk, dinv, hs, N);

  const int nwaves1 = (N + 1) / 2;  // 2 nodes per wave
  k_gather_fused<<<(nwaves1 * 64 + 255) / 256, 256, 0, stream>>>(rowptr, csr_src, dinv, hs,
                                                                 b1, W2, maskb, zs, N);
  const int nwaves2 = (N + 3) / 4;  // 4 nodes per wave
  k_gather2<<<(nwaves2 * 64 + 255) / 256, 256, 0, stream>>>(rowptr, csr_src, dinv, zs, b2, out, N);
}

// Round 3
// 338.186 us; speedup vs baseline: 1.1436x; 1.1436x over previous
//
#include <hip/hip_runtime.h>
#include <stdint.h>

// ---------------------------------------------------------------------------
// GCN 2-layer: out = Ahat( dropout(elu( Ahat(x@W1)+b1 )) @ W2 ) + b2
// Ahat = D^-1/2 (A+I) D^-1/2
// dropout = jax threefry2x32 key(42), p=0.25, partitionable path.
// R12->R13: GEMM re-restructured. R12's per-lane direct A loads killed
// coalescing (105us, HBM 9%). R11's coalesced staging was right; its 16x
// (vmcnt(0)+barrier) drains were the problem. K=512 is small enough that the
// WHOLE 64-row A tile fits LDS (64x512 fp16 = 64KB exactly): stage all of it
// once (coalesced, 16 pipelined load->cvt->ds_write iters, no barriers
// between), ONE __syncthreads, then 16 K-steps of pure {L2-hot B loads +
// ds_read_b128 + MFMA} with zero barriers. LDS XOR-swizzle byte^=(row&7)<<4
// on both write and read: read phases 2-way (free), write 4-way (16 instrs).
// ---------------------------------------------------------------------------

typedef float floatx4 __attribute__((ext_vector_type(4)));
typedef _Float16 f16;
typedef _Float16 f16x8 __attribute__((ext_vector_type(8)));

union F16x8 {
  f16x8 v;
  f16 e[8];
  uint4 q;
};

// ---------------- Threefry-2x32, key = (0, 42), 20 rounds ------------------
__device__ __forceinline__ void tf_round(uint32_t& x0, uint32_t& x1, int r) {
  x0 += x1;
  x1 = (x1 << r) | (x1 >> (32 - r));
  x1 ^= x0;
}

__device__ __forceinline__ void threefry_0_42(uint32_t c0, uint32_t c1,
                                              uint32_t& o0, uint32_t& o1) {
  const uint32_t ks0 = 0u;
  const uint32_t ks1 = 42u;
  const uint32_t ks2 = 0x1BD11BDAu ^ 0u ^ 42u;
  uint32_t x0 = c0 + ks0;
  uint32_t x1 = c1 + ks1;
  tf_round(x0, x1, 13); tf_round(x0, x1, 15); tf_round(x0, x1, 26); tf_round(x0, x1, 6);
  x0 += ks1; x1 += ks2 + 1u;
  tf_round(x0, x1, 17); tf_round(x0, x1, 29); tf_round(x0, x1, 16); tf_round(x0, x1, 24);
  x0 += ks2; x1 += ks0 + 2u;
  tf_round(x0, x1, 13); tf_round(x0, x1, 15); tf_round(x0, x1, 26); tf_round(x0, x1, 6);
  x0 += ks0; x1 += ks1 + 3u;
  tf_round(x0, x1, 17); tf_round(x0, x1, 29); tf_round(x0, x1, 16); tf_round(x0, x1, 24);
  x0 += ks1; x1 += ks2 + 4u;
  tf_round(x0, x1, 13); tf_round(x0, x1, 15); tf_round(x0, x1, 26); tf_round(x0, x1, 6);
  x0 += ks2; x1 += ks0 + 5u;
  o0 = x0; o1 = x1;
}

// mask byte for features [8b, 8b+8): bit i set = keep (u < 0.75)
__device__ __forceinline__ unsigned char mask_byte(uint32_t b) {
  uint32_t jb = b << 3;
  uint32_t m = 0;
#pragma unroll
  for (int i = 0; i < 8; ++i) {
    uint32_t r0, r1;
    threefry_0_42(0u, jb + (uint32_t)i, r0, r1);
    uint32_t bits = r0 ^ r1;
    // u = bitcast((bits>>9)|0x3f800000)-1 < 0.75  <=>  bits < 0xC0000000 (exact)
    m |= (bits < 0xC0000000u ? 1u : 0u) << i;
  }
  return (unsigned char)m;
}

// ---------------- degree (+ dropout-mask bytes [0,nb0)) --------------------
__global__ void k_deg(const int* __restrict__ dst, int E, int* __restrict__ deg,
                      unsigned char* __restrict__ maskb, int nb0) {
  int t = blockIdx.x * blockDim.x + threadIdx.x;
  if (t < E) atomicAdd(&deg[dst[t]], 1);
  if (t < nb0) maskb[t] = mask_byte((uint32_t)t);
}

// ---------------- 3-phase exclusive scan (+ dinv fused) --------------------
__global__ __launch_bounds__(256) void k_scan1(const int* __restrict__ deg,
                                               int* __restrict__ excl,
                                               int* __restrict__ sums,
                                               float* __restrict__ dinv, int N) {
  __shared__ int sm[256];
  int tid = threadIdx.x;
  int i = blockIdx.x * 256 + tid;
  int v = (i < N) ? deg[i] : 0;
  if (i < N) dinv[i] = 1.0f / sqrtf((float)(v + 1));  // +1 self loop
  sm[tid] = v;
  __syncthreads();
#pragma unroll
  for (int off = 1; off < 256; off <<= 1) {
    int t = (tid >= off) ? sm[tid - off] : 0;
    __syncthreads();
    sm[tid] += t;
    __syncthreads();
  }
  if (i < N) excl[i] = sm[tid] - v;
  if (tid == 255) sums[blockIdx.x] = sm[255];
}

__global__ __launch_bounds__(1024) void k_scan2(int* __restrict__ sums, int nb) {
  __shared__ int sm[1024];
  int tid = threadIdx.x;
  int v = (tid < nb) ? sums[tid] : 0;
  sm[tid] = v;
  __syncthreads();
#pragma unroll
  for (int off = 1; off < 1024; off <<= 1) {
    int t = (tid >= off) ? sm[tid - off] : 0;
    __syncthreads();
    sm[tid] += t;
    __syncthreads();
  }
  if (tid < nb) sums[tid] = sm[tid] - v;  // exclusive, in place
}

__global__ void k_scan3(int* __restrict__ rowptr, int* __restrict__ cursor,
                        const int* __restrict__ sums, int N, int E) {
  int i = blockIdx.x * blockDim.x + threadIdx.x;
  if (i < N) {
    int r = rowptr[i] + sums[i >> 8];
    rowptr[i] = r;
    cursor[i] = r;
  }
  if (i == 0) rowptr[N] = E;
}

// ---------------- bucket edges by dst (+ mask bytes [nb0,nb0+nb1)) ---------
__global__ void k_bucket(const int* __restrict__ src, const int* __restrict__ dst,
                         int* __restrict__ cursor, int* __restrict__ csr_src, int E,
                         unsigned char* __restrict__ maskb, int nb0, int nb1) {
  int t = blockIdx.x * blockDim.x + threadIdx.x;
  if (t < E) {
    int pos = atomicAdd(&cursor[dst[t]], 1);
    csr_src[pos] = src[t];
  }
  if (t < nb1) maskb[nb0 + t] = mask_byte((uint32_t)(nb0 + t));
}

// -------- prep: W1 [512][256] fp32 -> packed fragment-major fp16 -----------
// uint4 entry index = (ks*16 + nt)*64 + lane; 8 fp16 each.
// lane = quad*16 + (n&15), k = ks*32 + quad*8 + j, nt = n>>4.
__global__ void k_prep_w1t(const float* __restrict__ W1,
                           f16* __restrict__ Bpk) {
  int t = blockIdx.x * blockDim.x + threadIdx.x;  // t = k*256+n
  if (t >= 512 * 256) return;
  int k = t >> 8, n = t & 255;
  int ks = k >> 5, quad = (k >> 3) & 3, j = k & 7;
  int nt = n >> 4, lane = quad * 16 + (n & 15);
  size_t e = ((size_t)(ks * 16 + nt)) * 64 + lane;
  Bpk[e * 8 + j] = (f16)W1[t];
}

// -------- GEMM1: hs = (f16) dinv ⊙ (x @ W1), single fp16 MFMA --------------
// Block tile 64 rows x 256 cols, 4 waves (wave = 64 rows x 64 cols).
// Full-K LDS staging: 64 x 512 fp16 = 64 KB, XOR-swizzled, staged once with
// coalesced loads (fp32 -> fp16 at staging), ONE barrier, then 16 K-steps
// barrier-free: B from packed L2-resident plane, A via ds_read_b128 (2-way
// bank pattern = free), MFMA.
__global__ __launch_bounds__(256) void k_gemm_mfma(
    const float* __restrict__ A,     // [M,512]
    const uint4* __restrict__ Bpk,   // packed fp16, 16384 uint4 (256 KB)
    const float* __restrict__ dinv,  // [M]
    f16* __restrict__ C,             // [M,256] scaled output
    int M) {
  __shared__ char As[64 * 1024];     // 64 rows x 512 fp16 (1024 B/row), swizzled
  const int tid = threadIdx.x;
  const int cg = tid >> 6;           // wave id = column group (nt = cg*4..+3)
  const int lane = tid & 63;
  const int quad = lane >> 4;
  const int l16 = lane & 15;
  const int m0 = blockIdx.x * 64;

  auto cvt8 = [](float4 a, float4 b) {
    F16x8 r;
    r.e[0] = (f16)a.x; r.e[1] = (f16)a.y; r.e[2] = (f16)a.z; r.e[3] = (f16)a.w;
    r.e[4] = (f16)b.x; r.e[5] = (f16)b.y; r.e[6] = (f16)b.z; r.e[7] = (f16)b.w;
    return r;
  };

  // ---- staging: thread t -> row t>>2, col-quad t&3; 16 ks iterations ------
  // (independent load->cvt->ds_write chains; compiler pipelines with counted
  // vmcnt; no barriers until the single one below)
  {
    const int srow = tid >> 2;
    const int scq = tid & 3;
    int grow = m0 + srow;
    if (grow >= M) grow = M - 1;
    const float* gsp = A + (size_t)grow * 512 + scq * 8;
    char* lbase = As + srow * 1024;
    const int swz = (srow & 7) << 4;
#pragma unroll
    for (int ks = 0; ks < 16; ++ks) {
      float4 s0 = *(const float4*)(gsp + ks * 32);
      float4 s1 = *(const float4*)(gsp + ks * 32 + 4);
      *(uint4*)(lbase + ((scq * 16 + ks * 64) ^ swz)) = cvt8(s0, s1).q;
    }
  }
  __syncthreads();  // the ONLY barrier

  floatx4 acc[4][4];  // [row-frag][col-tile]
#pragma unroll
  for (int fr = 0; fr < 4; ++fr)
#pragma unroll
    for (int t = 0; t < 4; ++t) acc[fr][t] = (floatx4){0.f, 0.f, 0.f, 0.f};

  const uint4* bp0 = Bpk + lane + (size_t)(cg * 4) * 64;
  const int swzr = (l16 & 7) << 4;   // read-side swizzle (row&7 == l16&7)

#pragma unroll
  for (int ks = 0; ks < 16; ++ks) {
    // B fragments for this ks (coalesced 1KB loads, L2-hot; compiler hoists)
    const uint4* bp = bp0 + (size_t)ks * 1024;
    F16x8 bf[4];
#pragma unroll
    for (int t = 0; t < 4; ++t) bf[t].q = bp[t * 64];

#pragma unroll
    for (int fr = 0; fr < 4; ++fr) {
      const int row = fr * 16 + l16;
      F16x8 af;
      af.q = *(const uint4*)(As + row * 1024 + ((quad * 16 + ks * 64) ^ swzr));
#pragma unroll
      for (int t = 0; t < 4; ++t) {
        acc[fr][t] = __builtin_amdgcn_mfma_f32_16x16x32_f16(af.v, bf[t].v, acc[fr][t], 0, 0, 0);
      }
    }
  }

  // store hs = dinv[row] * acc; C/D layout col=lane&15, row=quad*4+reg
#pragma unroll
  for (int fr = 0; fr < 4; ++fr)
#pragma unroll
    for (int r = 0; r < 4; ++r) {
      int gm = m0 + fr * 16 + quad * 4 + r;
      if (gm < M) {
        float dv = dinv[gm];
#pragma unroll
        for (int t = 0; t < 4; ++t) {
          const int col = (cg * 4 + t) * 16 + l16;
          C[(size_t)gm * 256 + col] = (f16)(dv * acc[fr][t][r]);
        }
      }
    }
}

// ------- fused gather1 + (+b1 -> elu -> dropout -> dot W2) -----------------
// hs is pre-scaled by dinv. agg[d] = dd*(hs[d] + Σ hs[s]).
// one wave serves TWO nodes (half-wave each); lane covers 8 fp16 feats (16B).
// stores zs[d] = dd * z[d] (pre-scaled for layer-2 gather).
// Accumulation in packed fp16 (v_pk_add_f16); dropout mask from precomputed
// packed-bit table (1.6 MB, L2-hot) instead of in-kernel threefry.
__global__ __launch_bounds__(256) void k_gather_fused(
    const int* __restrict__ rowptr, const int* __restrict__ csr_src,
    const float* __restrict__ dinv, const f16* __restrict__ hs,
    const float* __restrict__ b1, const float* __restrict__ W2,
    const unsigned char* __restrict__ maskb,
    float* __restrict__ zs, int N) {
  int wave = (blockIdx.x * blockDim.x + threadIdx.x) >> 6;
  int lane = threadIdx.x & 63;
  int half = lane >> 5;
  int l = lane & 31;
  int d = wave * 2 + half;
  bool valid = d < N;
  if (!valid) d = N - 1;
  float dd = dinv[d];
  int beg = rowptr[d], end = rowptr[d + 1];
  int f0 = l << 3;  // 8 features per lane

  F16x8 accu;
  accu.q = *(const uint4*)(hs + ((size_t)d << 8) + f0);  // self term
  f16x8 accv = accu.v;

  int e = beg;
  // peel to 16B-aligned csr_src index loads (csr_src is 256B-aligned)
  {
    int pe = beg + ((4 - (beg & 3)) & 3);
    if (pe > end) pe = end;
    for (; e < pe; ++e) {
      F16x8 a;
      a.q = *(const uint4*)(hs + ((size_t)csr_src[e] << 8) + f0);
      accv = accv + a.v;
    }
  }
  for (; e + 3 < end; e += 4) {
    int4 s4 = *(const int4*)(csr_src + e);  // one dwordx4 for 4 indices
    F16x8 a, b, c, dq;
    a.q  = *(const uint4*)(hs + ((size_t)s4.x << 8) + f0);
    b.q  = *(const uint4*)(hs + ((size_t)s4.y << 8) + f0);
    c.q  = *(const uint4*)(hs + ((size_t)s4.z << 8) + f0);
    dq.q = *(const uint4*)(hs + ((size_t)s4.w << 8) + f0);
    f16x8 t0 = a.v + b.v;     // v_pk_add_f16 x4
    f16x8 t1 = c.v + dq.v;
    accv = accv + (t0 + t1);
  }
  for (; e < end; ++e) {
    F16x8 a;
    a.q = *(const uint4*)(hs + ((size_t)csr_src[e] << 8) + f0);
    accv = accv + a.v;
  }
  accu.v = accv;

  // epilogue: scale by dd, bias, elu, masked dropout, dot W2
  float4 bb0 = *(const float4*)(b1 + f0);
  float4 bb1 = *(const float4*)(b1 + f0 + 4);
  float4 w0  = *(const float4*)(W2 + f0);
  float4 w1  = *(const float4*)(W2 + f0 + 4);
  const float* bbp[8] = {&bb0.x, &bb0.y, &bb0.z, &bb0.w, &bb1.x, &bb1.y, &bb1.z, &bb1.w};
  const float* wp[8]  = {&w0.x, &w0.y, &w0.z, &w0.w, &w1.x, &w1.y, &w1.z, &w1.w};

  uint32_t mb = maskb[(size_t)d * 32 + l];  // 8 keep-bits for this lane

  float sum = 0.f;
#pragma unroll
  for (int i = 0; i < 8; ++i) {
    float va = dd * (float)accu.e[i] + *bbp[i];
    float ea = va > 0.f ? va : (__expf(va) - 1.0f);  // elu (fast exp)
    float ha = ((mb >> i) & 1u) ? (ea * (1.0f / 0.75f)) : 0.f;
    sum += ha * *wp[i];
  }
#pragma unroll
  for (int off = 16; off > 0; off >>= 1) sum += __shfl_down(sum, off, 32);
  if (l == 0 && valid) zs[d] = dd * sum;
}

// ------- gather layer 2: out[d] = b2 + dd*(zs[d] + Σ zs[s]) ----------------
// 4 nodes per wave (16 lanes each; avg degree ~16)
__global__ __launch_bounds__(256) void k_gather2(
    const int* __restrict__ rowptr, const int* __restrict__ csr_src,
    const float* __restrict__ dinv, const float* __restrict__ zs,
    const float* __restrict__ b2, float* __restrict__ out, int N) {
  int wave = (blockIdx.x * blockDim.x + threadIdx.x) >> 6;
  int lane = threadIdx.x & 63;
  int sub = lane >> 4;   // 0..3
  int l = lane & 15;
  int d = wave * 4 + sub;
  bool valid = d < N;
  if (!valid) d = N - 1;
  float dd = dinv[d];
  int beg = rowptr[d], end = rowptr[d + 1];

  float acc = 0.f;
  for (int e = beg + l; e < end; e += 16) {
    acc += zs[csr_src[e]];
  }
#pragma unroll
  for (int off = 8; off > 0; off >>= 1) acc += __shfl_down(acc, off, 16);
  if (l == 0 && valid) out[d] = b2[0] + dd * (zs[d] + acc);
}

// ---------------------------------------------------------------------------
extern "C" void kernel_launch(void* const* d_in, const int* in_sizes, int n_in,
                              void* d_out, int out_size, void* d_ws, size_t ws_size,
                              hipStream_t stream) {
  const float* x  = (const float*)d_in[0];
  const int*   ei = (const int*)d_in[1];   // [2,E] int32
  const float* W1 = (const float*)d_in[2];
  const float* b1 = (const float*)d_in[3];
  const float* W2 = (const float*)d_in[4];
  const float* b2 = (const float*)d_in[5];
  float* out = (float*)d_out;

  const int E = in_sizes[1] / 2;
  const int N = in_sizes[0] / 512;  // 50000
  const int* src = ei;
  const int* dst = ei + E;

  char* ws = (char*)d_ws;
  size_t off = 0;
  auto alloc = [&](size_t bytes) -> void* {
    void* p = ws + off;
    off += (bytes + 255) & ~(size_t)255;
    return p;
  };
  int*   deg     = (int*)  alloc((size_t)N * 4);
  int*   rowptr  = (int*)  alloc((size_t)(N + 1) * 4);
  int*   cursor  = (int*)  alloc((size_t)N * 4);
  int*   csr_src = (int*)  alloc((size_t)E * 4);          // 3.2 MB
  int*   sums    = (int*)  alloc(1024 * 4);
  float* dinv    = (float*)alloc((size_t)N * 4);
  f16*   hs      = (f16*)  alloc((size_t)N * 256 * 2);    // 25.6 MB
  float* zs      = (float*)alloc((size_t)N * 4);
  f16*   Bpk     = (f16*)  alloc(512 * 256 * 2);          // 256 KB packed W1
  unsigned char* maskb = (unsigned char*)alloc((size_t)N * 32);  // 1.6 MB mask

  const int nb = (N + 255) / 256;  // scan blocks

  // dropout mask bytes: N*32 total, split across k_deg (first half) and
  // k_bucket (second half) -- both are atomic-latency-bound, VALU idle.
  const int nbytes = N * 32;
  const int nb0 = nbytes >> 1;
  const int nb1 = nbytes - nb0;
  const int tdeg = (E > nb0) ? E : nb0;
  const int tbkt = (E > nb1) ? E : nb1;

  hipMemsetAsync(deg, 0, (size_t)N * 4, stream);
  k_prep_w1t<<<(512 * 256 + 255) / 256, 256, 0, stream>>>(W1, Bpk);
  k_deg<<<(tdeg + 255) / 256, 256, 0, stream>>>(dst, E, deg, maskb, nb0);
  k_scan1<<<nb, 256, 0, stream>>>(deg, rowptr, sums, dinv, N);
  k_scan2<<<1, 1024, 0, stream>>>(sums, nb);
  k_scan3<<<(N + 255) / 256, 256, 0, stream>>>(rowptr, cursor, sums, N, E);
  k_bucket<<<(tbkt + 255) / 256, 256, 0, stream>>>(src, dst, cursor, csr_src, E,
                                                   maskb, nb0, nb1);

  k_gemm_mfma<<<(N + 63) / 64, 256, 0, stream>>>(x, (const uint4*)Bpk, dinv, hs, N);

  const int nwaves1 = (N + 1) / 2;  // 2 nodes per wave
  k_gather_fused<<<(nwaves1 * 64 + 255) / 256, 256, 0, stream>>>(rowptr, csr_src, dinv, hs,
                                                                 b1, W2, maskb, zs, N);
  const int nwaves2 = (N + 3) / 4;  // 4 nodes per wave
  k_gather2<<<(nwaves2 * 64 + 255) / 256, 256, 0, stream>>>(rowptr, csr_src, dinv, zs, b2, out, N);
}